// Round 3
// baseline (835.312 us; speedup 1.0000x reference)
//
#include <hip/hip_runtime.h>
#include <hip/hip_bf16.h>

// Problem constants
#define C_CLASS 64
#define C_GROUPS 8
#define C_GSIZE 32
#define C_D 2048      // IN_CH
#define C_O 256       // OUT_CH
#define C_P 5         // NUM_PROTO
#define C_M (C_CLASS*C_GROUPS*C_GSIZE)   // 16384 rows of feats

typedef __bf16 bf16;
typedef bf16 bf16x8 __attribute__((ext_vector_type(8)));
typedef bf16 bf16x4 __attribute__((ext_vector_type(4)));
typedef float floatx4 __attribute__((ext_vector_type(4)));

// async 16B global->LDS (LDS dest must be wave-uniform base + lane*16)
__device__ __forceinline__ void gl_lds16(const bf16* g, bf16* l) {
    __builtin_amdgcn_global_load_lds(
        (const __attribute__((address_space(1))) void*)g,
        (__attribute__((address_space(3))) void*)l, 16, 0, 0);
}

// ---------------- merged fp32 -> bf16 weight conversion (T, W1, Wi1, W2) ----------------
__global__ __launch_bounds__(256) void convw_kernel(const float* __restrict__ T,
                                                    const float* __restrict__ W1,
                                                    const float* __restrict__ Wi1,
                                                    const float* __restrict__ W2,
                                                    bf16* __restrict__ Tb,
                                                    bf16* __restrict__ W1b,
                                                    bf16* __restrict__ Wi1b,
                                                    bf16* __restrict__ W2b) {
    const int nT = C_D * C_D / 4;
    const int nW = C_O * C_D / 4;
    int i = blockIdx.x * 256 + threadIdx.x;
    const float* s; bf16* d; int j;
    if (i < nT)               { s = T;   d = Tb;   j = i; }
    else if (i < nT + nW)     { s = W1;  d = W1b;  j = i - nT; }
    else if (i < nT + 2 * nW) { s = Wi1; d = Wi1b; j = i - nT - nW; }
    else                      { s = W2;  d = W2b;  j = i - nT - 2 * nW; }
    float4 v = ((const float4*)s)[j];
    bf16x4 b;
    b[0] = (bf16)v.x; b[1] = (bf16)v.y; b[2] = (bf16)v.z; b[3] = (bf16)v.w;
    ((bf16x4*)d)[j] = b;
}

// ---------------- big GEMM: Yb = bf16(residb + relu(ctx . T^T)) ----------------
// R2: read-pipelined 2-half schedule. R1's 4-phase put ds_reads and MFMA on the
// same side of lgkmcnt(0) -> LDS pipe (~300cyc/phase) and matrix pipe (~154) took
// turns (MfmaUtil 36%). Now A-frags are loaded one half-K-tile AHEAD into a
// second named register set, issued AFTER the bfr reads so the compiler's FIFO
// lgkmcnt wait before MFMA leaves them outstanding -> they drain UNDER the MFMAs.
//   afA = kh0 frags (loaded at prev odd half), afB = kh1 frags (loaded at even half).
// Per tile t (buf=t&1):
//   even: bfr(kh0,4) ; afB(kh1,8) ; stage t+1-kh1(4) ; MFMA kh0 x32 ; barrier B1
//   odd : stage t+2-kh0(4) ; vmcnt(st2?4:0)+barrier B2 ; bfr(kh1,4) ;
//         afA(t+1-kh0,8) ; MFMA kh1 x32 ; barrier B3
// vmcnt ledger (groups of 4): t+1-kh1 issued t-even, drained t-B2; t+1-kh0 issued
// t-1-odd, drained t-B2. Tail t=NT-2 drains to 0 (no t-odd group to count).
// XCD-chunked square raster kept from R1 (FETCH 303->131MB).
__global__ __launch_bounds__(512, 2) void gemm_relu(const bf16* __restrict__ A,
                                                    const bf16* __restrict__ B,
                                                    const bf16* __restrict__ residb,
                                                    bf16* __restrict__ Cb) {
    // [buf][kh][half][128*32] ; A halves = m 0..127 / 128..255, B halves = n halves
    __shared__ bf16 sA[2][2][2][4096];
    __shared__ bf16 sB[2][2][2][4096];

    const int tid = threadIdx.x;
    const int bid = blockIdx.x;
    const int xcd = bid & 7;
    const int loc = bid >> 3;                    // 0..63 within XCD
    const int m0  = ((xcd << 3) + (loc >> 3)) << 8;
    const int n0  = (loc & 7) << 8;

    const int w    = tid >> 6;        // wave 0..7
    const int lane = tid & 63;
    const int rr   = lane & 15;
    const int q    = lane >> 4;       // 0..3
    const int mh_w = w >> 2;          // this wave's A m-half
    const int nh_w = (w >> 1) & 1;    // this wave's B n-half
    const int wm   = mh_w * 128;
    const int wn   = (w & 3) * 64;
    const int brow = (w & 1) * 64;    // B row base within n-half unit
    const int csw  = (q ^ ((rr >> 1) & 3)) * 8;   // swizzled read chunk

    // staging source (per-thread): row sr, swizzled col chunk sc within a unit
    const int sr = tid >> 2;                           // 0..127
    const int sc = ((tid & 3) ^ ((sr >> 1) & 3)) * 8;  // inverse of read swizzle
    const bf16* aS0 = A + (long)(m0 + sr) * C_D + sc;        // A m-half 0
    const bf16* aS1 = A + (long)(m0 + 128 + sr) * C_D + sc;  // A m-half 1
    const bf16* bS0 = B + (long)(n0 + sr) * C_D + sc;        // B n-half 0
    const bf16* bS1 = B + (long)(n0 + 128 + sr) * C_D + sc;  // B n-half 1
    const int ld = tid * 8;            // linear LDS elem offset within a unit

    floatx4 acc[8][4];
#pragma unroll
    for (int i = 0; i < 8; i++)
#pragma unroll
        for (int j = 0; j < 4; j++) acc[i][j] = (floatx4){0.f, 0.f, 0.f, 0.f};

    const int NT = C_D / 64;   // 32 K-tiles
    bf16x8 afA[8], afB[8];     // kh0 / kh1 A-frag register sets

    // ---- prologue: stage t0 (both kh) + t1-kh0; drain t0; preload afA(t0-kh0) ----
    gl_lds16(aS0,      &sA[0][0][0][ld]);
    gl_lds16(aS1,      &sA[0][0][1][ld]);
    gl_lds16(bS0,      &sB[0][0][0][ld]);
    gl_lds16(bS1,      &sB[0][0][1][ld]);
    gl_lds16(aS0 + 32, &sA[0][1][0][ld]);
    gl_lds16(aS1 + 32, &sA[0][1][1][ld]);
    gl_lds16(bS0 + 32, &sB[0][1][0][ld]);
    gl_lds16(bS1 + 32, &sB[0][1][1][ld]);
    gl_lds16(aS0 + 64, &sA[1][0][0][ld]);
    gl_lds16(aS1 + 64, &sA[1][0][1][ld]);
    gl_lds16(bS0 + 64, &sB[1][0][0][ld]);
    gl_lds16(bS1 + 64, &sB[1][0][1][ld]);
    asm volatile("s_waitcnt vmcnt(4)" ::: "memory");   // drain t0-kh0, t0-kh1
    __builtin_amdgcn_s_barrier();
    {
        const bf16* bA = &sA[0][0][mh_w][0];
#pragma unroll
        for (int i = 0; i < 8; i++)
            afA[i] = *(const bf16x8*)&bA[(16 * i + rr) * 32 + csw];
    }

    auto tileBody = [&](int t, int buf) {
        const int nbuf = buf ^ 1;
        const long k1 = (long)(t + 1) * 64;
        const long k2 = (long)(t + 2) * 64;
        const bool st1 = (t < NT - 1);
        const bool st2 = (t < NT - 2);
        bf16x8 bfr[4];

        // ---------- even half: kh0 ----------
        {
            const bf16* bB = &sB[buf][0][nh_w][0];
#pragma unroll
            for (int j = 0; j < 4; j++)
                bfr[j] = *(const bf16x8*)&bB[(brow + 16 * j + rr) * 32 + csw];
            // read-ahead: kh1 A-frags (drain under the kh0 MFMAs)
            const bf16* bA1 = &sA[buf][1][mh_w][0];
#pragma unroll
            for (int i = 0; i < 8; i++)
                afB[i] = *(const bf16x8*)&bA1[(16 * i + rr) * 32 + csw];
            if (st1) {
                gl_lds16(aS0 + k1 + 32, &sA[nbuf][1][0][ld]);
                gl_lds16(aS1 + k1 + 32, &sA[nbuf][1][1][ld]);
                gl_lds16(bS0 + k1 + 32, &sB[nbuf][1][0][ld]);
                gl_lds16(bS1 + k1 + 32, &sB[nbuf][1][1][ld]);
            }
            __builtin_amdgcn_s_setprio(1);
#pragma unroll
            for (int i = 0; i < 8; i++)
#pragma unroll
                for (int j = 0; j < 4; j++)
                    acc[i][j] = __builtin_amdgcn_mfma_f32_16x16x32_bf16(afA[i], bfr[j], acc[i][j], 0, 0, 0);
            __builtin_amdgcn_s_setprio(0);
            __builtin_amdgcn_s_barrier();   // B1: kh0 region free
        }
        // ---------- odd half: kh1 ----------
        {
            if (st2) {
                gl_lds16(aS0 + k2, &sA[buf][0][0][ld]);
                gl_lds16(aS1 + k2, &sA[buf][0][1][ld]);
                gl_lds16(bS0 + k2, &sB[buf][0][0][ld]);
                gl_lds16(bS1 + k2, &sB[buf][0][1][ld]);
                asm volatile("s_waitcnt vmcnt(4)" ::: "memory");
            } else {
                asm volatile("s_waitcnt vmcnt(0)" ::: "memory");
            }
            __builtin_amdgcn_s_barrier();   // B2: t+1-kh0 / t+1-kh1 data ready
            const bf16* bB = &sB[buf][1][nh_w][0];
#pragma unroll
            for (int j = 0; j < 4; j++)
                bfr[j] = *(const bf16x8*)&bB[(brow + 16 * j + rr) * 32 + csw];
            if (st1) {
                // read-ahead: next tile's kh0 A-frags (drain under the kh1 MFMAs)
                const bf16* bA0 = &sA[nbuf][0][mh_w][0];
#pragma unroll
                for (int i = 0; i < 8; i++)
                    afA[i] = *(const bf16x8*)&bA0[(16 * i + rr) * 32 + csw];
            }
            __builtin_amdgcn_s_setprio(1);
#pragma unroll
            for (int i = 0; i < 8; i++)
#pragma unroll
                for (int j = 0; j < 4; j++)
                    acc[i][j] = __builtin_amdgcn_mfma_f32_16x16x32_bf16(afB[i], bfr[j], acc[i][j], 0, 0, 0);
            __builtin_amdgcn_s_setprio(0);
            __builtin_amdgcn_s_barrier();   // B3: kh1 region free (tile end)
        }
    };

#pragma unroll 1
    for (int tt = 0; tt < NT; tt += 2) {
        tileBody(tt,     0);
        tileBody(tt + 1, 1);
    }

    // ---------- epilogue: Yb = bf16(resid + relu(acc)) ----------
    const int cn    = lane & 15;
    const int rbase = q * 4;
#pragma unroll
    for (int i = 0; i < 8; i++) {
#pragma unroll
        for (int j = 0; j < 4; j++) {
            int gn = n0 + wn + j * 16 + cn;
#pragma unroll
            for (int r = 0; r < 4; r++) {
                int gm = m0 + wm + i * 16 + rbase + r;
                long idx = (long)gm * C_D + gn;
                Cb[idx] = (bf16)((float)residb[idx] + fmaxf(acc[i][j][r], 0.f));
            }
        }
    }
}

// ---------------- 64x128 NT GEMM (N=256, K=2048), fp32 out ----------------
// AF32=1: A fp32, converted during staging; n0==0 blocks optionally emit Xout (bf16).
template<int AF32>
__global__ __launch_bounds__(256) void gemm64(const void* __restrict__ Av,
                                              const bf16* __restrict__ B,
                                              float* __restrict__ Cf,
                                              bf16* __restrict__ Xout) {
    __shared__ bf16 sA[64 * 64];
    __shared__ bf16 sB[128 * 64];

    const int tid  = threadIdx.x;
    const int m0   = blockIdx.x * 64;
    const int n0   = blockIdx.y * 128;
    const int lane = tid & 63;
    const int wave = tid >> 6;
    const int wm   = (wave >> 1) * 32;
    const int wn   = (wave & 1) * 64;

    const int r0 = tid >> 3;
    const int cw = (tid & 7) ^ (r0 & 7);
    const float* aPf = (const float*)Av + (long)(m0 + r0) * C_D + cw * 8;
    const bf16*  aPb = (const bf16*)Av + (long)(m0 + r0) * C_D + cw * 8;
    const bf16*  bP  = B + (long)(n0 + r0) * C_D + cw * 8;
    const bool   wrX = AF32 && (n0 == 0) && (Xout != nullptr);

    floatx4 acc[2][4];
#pragma unroll
    for (int i = 0; i < 2; i++)
#pragma unroll
        for (int j = 0; j < 4; j++) acc[i][j] = (floatx4){0.f, 0.f, 0.f, 0.f};

    const int rr  = lane & 15;
    const int q   = lane >> 4;
    const int swz = lane & 7;
    const int co0 = (q ^ swz) * 8;
    const int co1 = ((q + 4) ^ swz) * 8;

    for (int k0 = 0; k0 < C_D; k0 += 64) {
        float4 xa[2][2];
        if (AF32) {
#pragma unroll
            for (int s = 0; s < 2; s++) {
                xa[s][0] = *(const float4*)(aPf + (long)(32 * s) * C_D + k0);
                xa[s][1] = *(const float4*)(aPf + (long)(32 * s) * C_D + k0 + 4);
            }
        }
        __syncthreads();
        if (AF32) {
#pragma unroll
            for (int s = 0; s < 2; s++) {
                bf16x8 v;
                v[0]=(bf16)xa[s][0].x; v[1]=(bf16)xa[s][0].y; v[2]=(bf16)xa[s][0].z; v[3]=(bf16)xa[s][0].w;
                v[4]=(bf16)xa[s][1].x; v[5]=(bf16)xa[s][1].y; v[6]=(bf16)xa[s][1].z; v[7]=(bf16)xa[s][1].w;
                *(bf16x8*)&sA[(tid + 256 * s) * 8] = v;
                if (wrX)
                    *(bf16x8*)&Xout[(long)(m0 + r0 + 32 * s) * C_D + k0 + cw * 8] = v;
            }
        } else {
#pragma unroll
            for (int s = 0; s < 2; s++)
                gl_lds16(aPb + (long)(32 * s) * C_D + k0, &sA[(tid + 256 * s) * 8]);
        }
#pragma unroll
        for (int s = 0; s < 4; s++)
            gl_lds16(bP + (long)(32 * s) * C_D + k0, &sB[(tid + 256 * s) * 8]);
        __syncthreads();

#pragma unroll
        for (int kh = 0; kh < 2; kh++) {
            const int co = kh ? co1 : co0;
            bf16x8 af[2], bff[4];
#pragma unroll
            for (int i = 0; i < 2; i++)
                af[i] = *(const bf16x8*)&sA[(wm + i * 16 + rr) * 64 + co];
#pragma unroll
            for (int j = 0; j < 4; j++)
                bff[j] = *(const bf16x8*)&sB[(wn + j * 16 + rr) * 64 + co];
#pragma unroll
            for (int i = 0; i < 2; i++)
#pragma unroll
                for (int j = 0; j < 4; j++)
                    acc[i][j] = __builtin_amdgcn_mfma_f32_16x16x32_bf16(af[i], bff[j], acc[i][j], 0, 0, 0);
        }
    }

    const int cn    = lane & 15;
    const int rbase = (lane >> 4) * 4;
#pragma unroll
    for (int i = 0; i < 2; i++)
#pragma unroll
        for (int j = 0; j < 4; j++) {
            int gn = n0 + wn + j * 16 + cn;
#pragma unroll
            for (int r = 0; r < 4; r++) {
                int gm = m0 + wm + i * 16 + rbase + r;
                Cf[(long)gm * C_O + gn] = acc[i][j][r];
            }
        }
}

// ---------------- per-(c,g) S + softmax -> att (bf16) ----------------
__global__ __launch_bounds__(256) void att_kernel(const float* __restrict__ e,
                                                  bf16* __restrict__ attb) {
    __shared__ float se[256][33];   // transposed: se[o][n]
    __shared__ float satt[32][33];
    const int g   = blockIdx.x;     // 0..511
    const int tid = threadIdx.x;
    const long R0 = (long)g * 32;

#pragma unroll
    for (int i = 0; i < 32; i++) se[tid][i] = e[(R0 + i) * 256 + tid];
    __syncthreads();

    {
        const int m  = tid & 31;
        const int nb = tid >> 5;
        float s0 = 0.f, s1 = 0.f, s2 = 0.f, s3 = 0.f;
        for (int o = 0; o < 256; o++) {
            float em = se[o][m];
            s0 += se[o][nb     ] * em;
            s1 += se[o][nb +  8] * em;
            s2 += se[o][nb + 16] * em;
            s3 += se[o][nb + 24] * em;
        }
        satt[nb     ][m] = s0 * (1.0f / 16.0f);
        satt[nb +  8][m] = s1 * (1.0f / 16.0f);
        satt[nb + 16][m] = s2 * (1.0f / 16.0f);
        satt[nb + 24][m] = s3 * (1.0f / 16.0f);
    }
    __syncthreads();

    if (tid < 32) {
        int n = tid;
        float mx = -1e30f;
        for (int m = 0; m < 32; m++) mx = fmaxf(mx, satt[n][m]);
        float sum = 0.f;
        for (int m = 0; m < 32; m++) { float v = __expf(satt[n][m] - mx); satt[n][m] = v; sum += v; }
        float inv = 1.0f / sum;
        for (int m = 0; m < 32; m++) satt[n][m] *= inv;
    }
    __syncthreads();

    // write att row-major [n][m] as bf16 (4 elems/thread, no row crossing: 4|32)
    {
        const int base = tid * 4;
        const int n = base >> 5, m = base & 31;
        bf16x4 v;
        v[0] = (bf16)satt[n][m];     v[1] = (bf16)satt[n][m + 1];
        v[2] = (bf16)satt[n][m + 2]; v[3] = (bf16)satt[n][m + 3];
        *(bf16x4*)&attb[(long)g * 1024 + base] = v;
    }
}

// ---------------- ctx = att @ X via MFMA, grid (512 groups, 8 d-chunks) ----------------
// Per block: [32x32]bf16 @ [32x256]bf16 -> ctx[32x256]. X tile staged in LDS with
// stride 258 (transposed B-frag reads conflict-free: quads offset 8 banks).
__global__ __launch_bounds__(256) void ctx_kernel(const bf16* __restrict__ attb,
                                                  const bf16* __restrict__ Xb,
                                                  bf16* __restrict__ ctx) {
    __shared__ bf16 sX[32 * 258];
    const int g   = blockIdx.x;
    const int dch = blockIdx.y;
    const int tid = threadIdx.x;
    const long R0 = (long)g * 32;
    const int d0  = dch * 256;

    // stage X tile [32 rows x 256 cols]
    {
        const int r  = tid >> 3;
        const int c0 = (tid & 7) * 32;
        const bf16* src = Xb + (R0 + r) * C_D + d0 + c0;
#pragma unroll
        for (int i = 0; i < 4; i++) {
            bf16x8 v = *(const bf16x8*)(src + i * 8);
            *(bf16x8*)&sX[r * 258 + c0 + i * 8] = v;
        }
    }
    __syncthreads();

    const int lane = tid & 63;
    const int wave = tid >> 6;
    const int rr   = lane & 15;
    const int q    = lane >> 4;

    // A-frags straight from global (att is L2-hot, 16B/lane)
    bf16x8 af[2];
#pragma unroll
    for (int i = 0; i < 2; i++)
        af[i] = *(const bf16x8*)&attb[(long)g * 1024 + (i * 16 + rr) * 32 + q * 8];

    floatx4 acc[2][4];
#pragma unroll
    for (int i = 0; i < 2; i++)
#pragma unroll
        for (int j = 0; j < 4; j++) acc[i][j] = (floatx4){0.f, 0.f, 0.f, 0.f};

#pragma unroll
    for (int j = 0; j < 4; j++) {
        const int dl = wave * 64 + j * 16 + rr;
        bf16x8 bf_;
#pragma unroll
        for (int jj = 0; jj < 8; jj++)
            bf_[jj] = sX[(q * 8 + jj) * 258 + dl];
#pragma unroll
        for (int i = 0; i < 2; i++)
            acc[i][j] = __builtin_amdgcn_mfma_f32_16x16x32_bf16(af[i], bf_, acc[i][j], 0, 0, 0);
    }

    const int rbase = q * 4;
#pragma unroll
    for (int i = 0; i < 2; i++)
#pragma unroll
        for (int j = 0; j < 4; j++)
#pragma unroll
            for (int r = 0; r < 4; r++)
                ctx[(R0 + i * 16 + rbase + r) * C_D + d0 + wave * 64 + j * 16 + rr]
                    = (bf16)acc[i][j][r];
}

// ---------------- att2: logits + softmax per class (64 blocks x 256) ----------------
__global__ __launch_bounds__(256) void att2_kernel(const float* __restrict__ p_e,
                                                   const float* __restrict__ fa_e,
                                                   float* __restrict__ att2f) {
    __shared__ float spe[5][256];
    __shared__ float red[256];
    __shared__ float att[5][256];
    const int c   = blockIdx.x;
    const int tid = threadIdx.x;

    for (int t = tid; t < 5 * 256; t += 256)
        spe[t >> 8][t & 255] = p_e[(long)c * 5 * 256 + t] * (1.0f / 16.0f);
    __syncthreads();

    // logits: thread = n, float4 over o
    {
        const float4* fa = (const float4*)(fa_e + ((long)c * 256 + tid) * 256);
        float acc[5] = {0.f, 0.f, 0.f, 0.f, 0.f};
        for (int o4 = 0; o4 < 64; o4++) {
            float4 f = fa[o4];
#pragma unroll
            for (int p = 0; p < 5; p++) {
                float4 s = *(const float4*)&spe[p][o4 * 4];
                acc[p] += s.x * f.x + s.y * f.y + s.z * f.z + s.w * f.w;
            }
        }
#pragma unroll
        for (int p = 0; p < 5; p++) att[p][tid] = acc[p];
    }
    __syncthreads();

    for (int p = 0; p < 5; p++) {
        float v = att[p][tid];
        red[tid] = v; __syncthreads();
        for (int s = 128; s > 0; s >>= 1) { if (tid < s) red[tid] = fmaxf(red[tid], red[tid + s]); __syncthreads(); }
        float mx = red[0]; __syncthreads();
        float ev = __expf(v - mx);
        red[tid] = ev; __syncthreads();
        for (int s = 128; s > 0; s >>= 1) { if (tid < s) red[tid] += red[tid + s]; __syncthreads(); }
        float sum = red[0]; __syncthreads();
        att2f[((long)c * 5 + p) * 256 + tid] = ev / sum;
    }
}

// ---------------- out = att2 @ Y, grid (64 classes, 8 d-chunks) x 256 ----------------
__global__ __launch_bounds__(256) void out_kernel(const float* __restrict__ att2f,
                                                  const bf16* __restrict__ Yb,
                                                  float* __restrict__ out) {
    __shared__ float s2[5][256];
    const int c   = blockIdx.x;
    const int ch  = blockIdx.y;
    const int tid = threadIdx.x;

    for (int t = tid; t < 5 * 256; t += 256)
        s2[t >> 8][t & 255] = att2f[(long)c * 5 * 256 + t];
    __syncthreads();

    const int d = ch * 256 + tid;
    const bf16* Yc = Yb + (long)c * C_O * C_D + d;
    float acc[5] = {0.f, 0.f, 0.f, 0.f, 0.f};
    for (int n4 = 0; n4 < 64; n4++) {
        float y0 = (float)Yc[(long)(n4 * 4 + 0) * C_D];
        float y1 = (float)Yc[(long)(n4 * 4 + 1) * C_D];
        float y2 = (float)Yc[(long)(n4 * 4 + 2) * C_D];
        float y3 = (float)Yc[(long)(n4 * 4 + 3) * C_D];
#pragma unroll
        for (int p = 0; p < 5; p++) {
            float4 a = *(const float4*)&s2[p][n4 * 4];
            acc[p] += a.x * y0 + a.y * y1 + a.z * y2 + a.w * y3;
        }
    }
#pragma unroll
    for (int p = 0; p < 5; p++)
        out[((long)c * 5 + p) * C_D + d] = acc[p];
}

extern "C" void kernel_launch(void* const* d_in, const int* in_sizes, int n_in,
                              void* d_out, int out_size, void* d_ws, size_t ws_size,
                              hipStream_t stream) {
    const float* X   = (const float*)d_in[0];
    const float* P   = (const float*)d_in[1];
    const float* W1  = (const float*)d_in[2];
    const float* T   = (const float*)d_in[3];
    const float* Wi1 = (const float*)d_in[4];
    const float* Wi2 = (const float*)d_in[5];
    float* out = (float*)d_out;

    char* ws = (char*)d_ws;
    size_t off = 0;
    auto alloc = [&](size_t bytes) -> void* {
        void* p = ws + off;
        off += (bytes + 255) & ~(size_t)255;
        return p;
    };
    const size_t NX = (size_t)C_M * C_D;
    bf16*  Xb   = (bf16*)alloc(NX * 2);
    bf16*  ctxb = (bf16*)alloc(NX * 2);
    bf16*  Tb   = (bf16*)alloc((size_t)C_D * C_D * 2);
    bf16*  W1b  = (bf16*)alloc((size_t)C_O * C_D * 2);
    bf16*  Wi1b = (bf16*)alloc((size_t)C_O * C_D * 2);
    bf16*  W2b  = (bf16*)alloc((size_t)C_O * C_D * 2);
    bf16*  Yb   = (bf16*)alloc(NX * 2);
    float* eBuf = (float*)alloc((size_t)C_M * C_O * 4);
    bf16*  attb = (bf16*)alloc((size_t)512 * 1024 * 2);   // aliased: att2f after ctx
    float* peBuf= (float*)alloc((size_t)C_CLASS * C_P * C_O * 4);
    float* faBuf = eBuf;            // e dead after att_kernel
    float* att2f = (float*)attb;    // attb dead after ctx_kernel (0.33MB < 1MB)

    // 1. weights -> bf16
    const int nConv4 = (C_D * C_D + 3 * C_O * C_D) / 4;
    convw_kernel<<<nConv4 / 256, 256, 0, stream>>>(T, W1, Wi1, Wi2, Tb, W1b, Wi1b, W2b);

    // 2. e = X . W1^T [16384,256]; n0==0 blocks emit Xb
    gemm64<1><<<dim3(C_M / 64, 2), 256, 0, stream>>>(X, W1b, eBuf, Xb);

    // 3. S + softmax -> att (bf16)
    att_kernel<<<C_CLASS * C_GROUPS, 256, 0, stream>>>(eBuf, attb);

    // 4. ctx = att @ X (batched MFMA)
    ctx_kernel<<<dim3(C_CLASS * C_GROUPS, 8), 256, 0, stream>>>(attb, Xb, ctxb);

    // 5. Y = bf16(Xb + relu(ctx . T^T)) — 256x256 tile, read-pipelined 2-half schedule
    gemm_relu<<<dim3((C_M / 256) * (C_D / 256)), 512, 0, stream>>>(ctxb, Tb, Xb, Yb);

    // 6. fa_e = Y . Wi1^T [16384,256]
    gemm64<0><<<dim3(C_M / 64, 2), 256, 0, stream>>>(Yb, Wi1b, faBuf, nullptr);

    // 7. p_e = P . W2^T [320,256] (M=320 = 5 blocks)
    gemm64<1><<<dim3(C_CLASS * C_P / 64, 2), 256, 0, stream>>>(P, W2b, peBuf, nullptr);

    // 8. att2 = softmax(p_e . fa_e^T / 16)
    att2_kernel<<<C_CLASS, 256, 0, stream>>>(peBuf, faBuf, att2f);

    // 9. out = att2 @ Y
    out_kernel<<<dim3(C_CLASS, 8), 256, 0, stream>>>(att2f, Yb, out);
}

// Round 4
// 552.742 us; speedup vs baseline: 1.5112x; 1.5112x over previous
//
#include <hip/hip_runtime.h>
#include <hip/hip_bf16.h>

// Problem constants
#define C_CLASS 64
#define C_GROUPS 8
#define C_GSIZE 32
#define C_D 2048      // IN_CH
#define C_O 256       // OUT_CH
#define C_P 5         // NUM_PROTO
#define C_M (C_CLASS*C_GROUPS*C_GSIZE)   // 16384 rows of feats

typedef __bf16 bf16;
typedef bf16 bf16x8 __attribute__((ext_vector_type(8)));
typedef bf16 bf16x4 __attribute__((ext_vector_type(4)));
typedef float floatx4 __attribute__((ext_vector_type(4)));

// async 16B global->LDS (LDS dest must be wave-uniform base + lane*16)
__device__ __forceinline__ void gl_lds16(const bf16* g, bf16* l) {
    __builtin_amdgcn_global_load_lds(
        (const __attribute__((address_space(1))) void*)g,
        (__attribute__((address_space(3))) void*)l, 16, 0, 0);
}

// ---------------- merged fp32 -> bf16 weight conversion (T, W1, Wi1, W2) ----------------
__global__ __launch_bounds__(256) void convw_kernel(const float* __restrict__ T,
                                                    const float* __restrict__ W1,
                                                    const float* __restrict__ Wi1,
                                                    const float* __restrict__ W2,
                                                    bf16* __restrict__ Tb,
                                                    bf16* __restrict__ W1b,
                                                    bf16* __restrict__ Wi1b,
                                                    bf16* __restrict__ W2b) {
    const int nT = C_D * C_D / 4;
    const int nW = C_O * C_D / 4;
    int i = blockIdx.x * 256 + threadIdx.x;
    const float* s; bf16* d; int j;
    if (i < nT)               { s = T;   d = Tb;   j = i; }
    else if (i < nT + nW)     { s = W1;  d = W1b;  j = i - nT; }
    else if (i < nT + 2 * nW) { s = Wi1; d = Wi1b; j = i - nT - nW; }
    else                      { s = W2;  d = W2b;  j = i - nT - 2 * nW; }
    float4 v = ((const float4*)s)[j];
    bf16x4 b;
    b[0] = (bf16)v.x; b[1] = (bf16)v.y; b[2] = (bf16)v.z; b[3] = (bf16)v.w;
    ((bf16x4*)d)[j] = b;
}

// ---------------- big GEMM: Yb = bf16(residb + relu(ctx . T^T)) ----------------
// R3: R1 skeleton (proven 157us, FETCH 131MB) with the serializers removed:
//  - NO explicit lgkmcnt(0): the compiler emits counted lgkmcnt(N) between
//    ds_read and MFMA (m97 evidence), so later af-reads drain UNDER earlier
//    MFMAs. R1's asm lgkmcnt(0) forced a full drain each phase (m141 failure
//    class). R2's double-register-set fix spilled (WRITE_SIZE 70MB->1.05GB).
//  - reads ordered bfr-first so the first MFMA depends only on reads #1-3.
//  - ONE barrier per phase (4/tile, was 8). Safe: phase-end barrier ==> all
//    waves' MFMAs done ==> all that phase's ds_reads complete, so staging into
//    regions dead-after-this-phase can't race them.
// vmcnt ledger (unchanged from R1, verified): 8 staging loads/tile; vmcnt(8)
// at ph2-end drains t-kh1 (read at t ph3), vmcnt(8) at ph4-end drains t+1-kh0
// (read at t+1 ph1); vmcnt before barrier gives cross-wave visibility.
// XCD-chunked square raster kept (A reused 8x, B 4x in each XCD's L2).
__global__ __launch_bounds__(512, 2) void gemm_relu(const bf16* __restrict__ A,
                                                    const bf16* __restrict__ B,
                                                    const bf16* __restrict__ residb,
                                                    bf16* __restrict__ Cb) {
    // [buf][kh][half][128*32] ; A halves = m 0..127 / 128..255, B halves = n halves
    __shared__ bf16 sA[2][2][2][4096];
    __shared__ bf16 sB[2][2][2][4096];

    const int tid = threadIdx.x;
    const int bid = blockIdx.x;
    const int xcd = bid & 7;
    const int loc = bid >> 3;                    // 0..63 within XCD
    const int m0  = ((xcd << 3) + (loc >> 3)) << 8;
    const int n0  = (loc & 7) << 8;

    const int w    = tid >> 6;        // wave 0..7
    const int lane = tid & 63;
    const int rr   = lane & 15;
    const int q    = lane >> 4;       // 0..3
    const int mh_w = w >> 2;          // this wave's A m-half
    const int nh_w = (w >> 1) & 1;    // this wave's B n-half
    const int wm   = mh_w * 128;
    const int wn   = (w & 3) * 64;
    const int brow = (w & 1) * 64;    // B row base within n-half unit
    const int csw  = (q ^ ((rr >> 1) & 3)) * 8;   // swizzled read chunk

    // staging source (per-thread): row sr, swizzled col chunk sc within a unit
    const int sr = tid >> 2;                           // 0..127
    const int sc = ((tid & 3) ^ ((sr >> 1) & 3)) * 8;  // inverse of read swizzle
    const bf16* aS0 = A + (long)(m0 + sr) * C_D + sc;        // A m-half 0
    const bf16* aS1 = A + (long)(m0 + 128 + sr) * C_D + sc;  // A m-half 1
    const bf16* bS0 = B + (long)(n0 + sr) * C_D + sc;        // B n-half 0
    const bf16* bS1 = B + (long)(n0 + 128 + sr) * C_D + sc;  // B n-half 1
    const int ld = tid * 8;            // linear LDS elem offset within a unit

    floatx4 acc[8][4];
#pragma unroll
    for (int i = 0; i < 8; i++)
#pragma unroll
        for (int j = 0; j < 4; j++) acc[i][j] = (floatx4){0.f, 0.f, 0.f, 0.f};

    const int NT = C_D / 64;   // 32 K-tiles

    // ---- prologue: stage t0 (kh0+kh1) + t1-kh0 (12 loads); drain t0-kh0 ----
    gl_lds16(aS0,      &sA[0][0][0][ld]);
    gl_lds16(aS1,      &sA[0][0][1][ld]);
    gl_lds16(bS0,      &sB[0][0][0][ld]);
    gl_lds16(bS1,      &sB[0][0][1][ld]);
    gl_lds16(aS0 + 32, &sA[0][1][0][ld]);
    gl_lds16(aS1 + 32, &sA[0][1][1][ld]);
    gl_lds16(bS0 + 32, &sB[0][1][0][ld]);
    gl_lds16(bS1 + 32, &sB[0][1][1][ld]);
    gl_lds16(aS0 + 64, &sA[1][0][0][ld]);
    gl_lds16(aS1 + 64, &sA[1][0][1][ld]);
    gl_lds16(bS0 + 64, &sB[1][0][0][ld]);
    gl_lds16(bS1 + 64, &sB[1][0][1][ld]);
    asm volatile("s_waitcnt vmcnt(8)" ::: "memory");   // drain t0-kh0
    __builtin_amdgcn_s_barrier();

    auto tileBody = [&](int t, int buf) {
        const int nbuf = buf ^ 1;
        const long k1 = (long)(t + 1) * 64;
        const long k2 = (long)(t + 2) * 64;
        const bool st1 = (t < NT - 1);
        const bool st2 = (t < NT - 2);
        bf16x8 af[8], bfr[2];

        // ---------- phase 1: kh0, j={0,1} ----------
        {
            const bf16* bA = &sA[buf][0][mh_w][0];
            const bf16* bB = &sB[buf][0][nh_w][0];
#pragma unroll
            for (int j = 0; j < 2; j++)
                bfr[j] = *(const bf16x8*)&bB[(brow + 16 * j + rr) * 32 + csw];
#pragma unroll
            for (int i = 0; i < 8; i++)
                af[i] = *(const bf16x8*)&bA[(16 * i + rr) * 32 + csw];
            if (st1) {
                gl_lds16(bS0 + k1 + 32, &sB[nbuf][1][0][ld]);
                gl_lds16(bS1 + k1 + 32, &sB[nbuf][1][1][ld]);
            }
            __builtin_amdgcn_s_setprio(1);
#pragma unroll
            for (int i = 0; i < 8; i++) {
                acc[i][0] = __builtin_amdgcn_mfma_f32_16x16x32_bf16(af[i], bfr[0], acc[i][0], 0, 0, 0);
                acc[i][1] = __builtin_amdgcn_mfma_f32_16x16x32_bf16(af[i], bfr[1], acc[i][1], 0, 0, 0);
            }
            __builtin_amdgcn_s_setprio(0);
            __builtin_amdgcn_s_barrier();
        }
        // ---------- phase 2: kh0, j={2,3} (af reused) ----------
        {
            const bf16* bB = &sB[buf][0][nh_w][0];
#pragma unroll
            for (int j = 0; j < 2; j++)
                bfr[j] = *(const bf16x8*)&bB[(brow + 16 * (j + 2) + rr) * 32 + csw];
            if (st1) {
                gl_lds16(aS0 + k1 + 32, &sA[nbuf][1][0][ld]);
                gl_lds16(aS1 + k1 + 32, &sA[nbuf][1][1][ld]);
            }
            __builtin_amdgcn_s_setprio(1);
#pragma unroll
            for (int i = 0; i < 8; i++) {
                acc[i][2] = __builtin_amdgcn_mfma_f32_16x16x32_bf16(af[i], bfr[0], acc[i][2], 0, 0, 0);
                acc[i][3] = __builtin_amdgcn_mfma_f32_16x16x32_bf16(af[i], bfr[1], acc[i][3], 0, 0, 0);
            }
            __builtin_amdgcn_s_setprio(0);
            if (st1) asm volatile("s_waitcnt vmcnt(8)" ::: "memory");
            else     asm volatile("s_waitcnt vmcnt(0)" ::: "memory");
            __builtin_amdgcn_s_barrier();
        }
        // ---------- phase 3: kh1, j={0,1} ----------
        {
            const bf16* bA = &sA[buf][1][mh_w][0];
            const bf16* bB = &sB[buf][1][nh_w][0];
#pragma unroll
            for (int j = 0; j < 2; j++)
                bfr[j] = *(const bf16x8*)&bB[(brow + 16 * j + rr) * 32 + csw];
#pragma unroll
            for (int i = 0; i < 8; i++)
                af[i] = *(const bf16x8*)&bA[(16 * i + rr) * 32 + csw];
            if (st2) {
                gl_lds16(aS0 + k2, &sA[buf][0][0][ld]);
                gl_lds16(bS0 + k2, &sB[buf][0][0][ld]);
            }
            __builtin_amdgcn_s_setprio(1);
#pragma unroll
            for (int i = 0; i < 8; i++) {
                acc[i][0] = __builtin_amdgcn_mfma_f32_16x16x32_bf16(af[i], bfr[0], acc[i][0], 0, 0, 0);
                acc[i][1] = __builtin_amdgcn_mfma_f32_16x16x32_bf16(af[i], bfr[1], acc[i][1], 0, 0, 0);
            }
            __builtin_amdgcn_s_setprio(0);
            __builtin_amdgcn_s_barrier();
        }
        // ---------- phase 4: kh1, j={2,3}; tile-end counted vmcnt ----------
        {
            const bf16* bB = &sB[buf][1][nh_w][0];
#pragma unroll
            for (int j = 0; j < 2; j++)
                bfr[j] = *(const bf16x8*)&bB[(brow + 16 * (j + 2) + rr) * 32 + csw];
            if (st2) {
                gl_lds16(aS1 + k2, &sA[buf][0][1][ld]);
                gl_lds16(bS1 + k2, &sB[buf][0][1][ld]);
            }
            __builtin_amdgcn_s_setprio(1);
#pragma unroll
            for (int i = 0; i < 8; i++) {
                acc[i][2] = __builtin_amdgcn_mfma_f32_16x16x32_bf16(af[i], bfr[0], acc[i][2], 0, 0, 0);
                acc[i][3] = __builtin_amdgcn_mfma_f32_16x16x32_bf16(af[i], bfr[1], acc[i][3], 0, 0, 0);
            }
            __builtin_amdgcn_s_setprio(0);
            if (st2) asm volatile("s_waitcnt vmcnt(8)" ::: "memory");
            else     asm volatile("s_waitcnt vmcnt(0)" ::: "memory");
            __builtin_amdgcn_s_barrier();
        }
    };

#pragma unroll 1
    for (int tt = 0; tt < NT; tt += 2) {
        tileBody(tt,     0);
        tileBody(tt + 1, 1);
    }

    // ---------- epilogue: Yb = bf16(resid + relu(acc)) ----------
    const int cn    = lane & 15;
    const int rbase = q * 4;
#pragma unroll
    for (int i = 0; i < 8; i++) {
#pragma unroll
        for (int j = 0; j < 4; j++) {
            int gn = n0 + wn + j * 16 + cn;
#pragma unroll
            for (int r = 0; r < 4; r++) {
                int gm = m0 + wm + i * 16 + rbase + r;
                long idx = (long)gm * C_D + gn;
                Cb[idx] = (bf16)((float)residb[idx] + fmaxf(acc[i][j][r], 0.f));
            }
        }
    }
}

// ---------------- 64x128 NT GEMM (N=256, K=2048), fp32 out ----------------
// AF32=1: A fp32, converted during staging; n0==0 blocks optionally emit Xout (bf16).
template<int AF32>
__global__ __launch_bounds__(256) void gemm64(const void* __restrict__ Av,
                                              const bf16* __restrict__ B,
                                              float* __restrict__ Cf,
                                              bf16* __restrict__ Xout) {
    __shared__ bf16 sA[64 * 64];
    __shared__ bf16 sB[128 * 64];

    const int tid  = threadIdx.x;
    const int m0   = blockIdx.x * 64;
    const int n0   = blockIdx.y * 128;
    const int lane = tid & 63;
    const int wave = tid >> 6;
    const int wm   = (wave >> 1) * 32;
    const int wn   = (wave & 1) * 64;

    const int r0 = tid >> 3;
    const int cw = (tid & 7) ^ (r0 & 7);
    const float* aPf = (const float*)Av + (long)(m0 + r0) * C_D + cw * 8;
    const bf16*  aPb = (const bf16*)Av + (long)(m0 + r0) * C_D + cw * 8;
    const bf16*  bP  = B + (long)(n0 + r0) * C_D + cw * 8;
    const bool   wrX = AF32 && (n0 == 0) && (Xout != nullptr);

    floatx4 acc[2][4];
#pragma unroll
    for (int i = 0; i < 2; i++)
#pragma unroll
        for (int j = 0; j < 4; j++) acc[i][j] = (floatx4){0.f, 0.f, 0.f, 0.f};

    const int rr  = lane & 15;
    const int q   = lane >> 4;
    const int swz = lane & 7;
    const int co0 = (q ^ swz) * 8;
    const int co1 = ((q + 4) ^ swz) * 8;

    for (int k0 = 0; k0 < C_D; k0 += 64) {
        float4 xa[2][2];
        if (AF32) {
#pragma unroll
            for (int s = 0; s < 2; s++) {
                xa[s][0] = *(const float4*)(aPf + (long)(32 * s) * C_D + k0);
                xa[s][1] = *(const float4*)(aPf + (long)(32 * s) * C_D + k0 + 4);
            }
        }
        __syncthreads();
        if (AF32) {
#pragma unroll
            for (int s = 0; s < 2; s++) {
                bf16x8 v;
                v[0]=(bf16)xa[s][0].x; v[1]=(bf16)xa[s][0].y; v[2]=(bf16)xa[s][0].z; v[3]=(bf16)xa[s][0].w;
                v[4]=(bf16)xa[s][1].x; v[5]=(bf16)xa[s][1].y; v[6]=(bf16)xa[s][1].z; v[7]=(bf16)xa[s][1].w;
                *(bf16x8*)&sA[(tid + 256 * s) * 8] = v;
                if (wrX)
                    *(bf16x8*)&Xout[(long)(m0 + r0 + 32 * s) * C_D + k0 + cw * 8] = v;
            }
        } else {
#pragma unroll
            for (int s = 0; s < 2; s++)
                gl_lds16(aPb + (long)(32 * s) * C_D + k0, &sA[(tid + 256 * s) * 8]);
        }
#pragma unroll
        for (int s = 0; s < 4; s++)
            gl_lds16(bP + (long)(32 * s) * C_D + k0, &sB[(tid + 256 * s) * 8]);
        __syncthreads();

#pragma unroll
        for (int kh = 0; kh < 2; kh++) {
            const int co = kh ? co1 : co0;
            bf16x8 af[2], bff[4];
#pragma unroll
            for (int i = 0; i < 2; i++)
                af[i] = *(const bf16x8*)&sA[(wm + i * 16 + rr) * 64 + co];
#pragma unroll
            for (int j = 0; j < 4; j++)
                bff[j] = *(const bf16x8*)&sB[(wn + j * 16 + rr) * 64 + co];
#pragma unroll
            for (int i = 0; i < 2; i++)
#pragma unroll
                for (int j = 0; j < 4; j++)
                    acc[i][j] = __builtin_amdgcn_mfma_f32_16x16x32_bf16(af[i], bff[j], acc[i][j], 0, 0, 0);
        }
    }

    const int cn    = lane & 15;
    const int rbase = (lane >> 4) * 4;
#pragma unroll
    for (int i = 0; i < 2; i++)
#pragma unroll
        for (int j = 0; j < 4; j++) {
            int gn = n0 + wn + j * 16 + cn;
#pragma unroll
            for (int r = 0; r < 4; r++) {
                int gm = m0 + wm + i * 16 + rbase + r;
                Cf[(long)gm * C_O + gn] = acc[i][j][r];
            }
        }
}

// ---------------- per-(c,g) S + softmax -> att (bf16) ----------------
__global__ __launch_bounds__(256) void att_kernel(const float* __restrict__ e,
                                                  bf16* __restrict__ attb) {
    __shared__ float se[256][33];   // transposed: se[o][n]
    __shared__ float satt[32][33];
    const int g   = blockIdx.x;     // 0..511
    const int tid = threadIdx.x;
    const long R0 = (long)g * 32;

#pragma unroll
    for (int i = 0; i < 32; i++) se[tid][i] = e[(R0 + i) * 256 + tid];
    __syncthreads();

    {
        const int m  = tid & 31;
        const int nb = tid >> 5;
        float s0 = 0.f, s1 = 0.f, s2 = 0.f, s3 = 0.f;
        for (int o = 0; o < 256; o++) {
            float em = se[o][m];
            s0 += se[o][nb     ] * em;
            s1 += se[o][nb +  8] * em;
            s2 += se[o][nb + 16] * em;
            s3 += se[o][nb + 24] * em;
        }
        satt[nb     ][m] = s0 * (1.0f / 16.0f);
        satt[nb +  8][m] = s1 * (1.0f / 16.0f);
        satt[nb + 16][m] = s2 * (1.0f / 16.0f);
        satt[nb + 24][m] = s3 * (1.0f / 16.0f);
    }
    __syncthreads();

    if (tid < 32) {
        int n = tid;
        float mx = -1e30f;
        for (int m = 0; m < 32; m++) mx = fmaxf(mx, satt[n][m]);
        float sum = 0.f;
        for (int m = 0; m < 32; m++) { float v = __expf(satt[n][m] - mx); satt[n][m] = v; sum += v; }
        float inv = 1.0f / sum;
        for (int m = 0; m < 32; m++) satt[n][m] *= inv;
    }
    __syncthreads();

    // write att row-major [n][m] as bf16 (4 elems/thread, no row crossing: 4|32)
    {
        const int base = tid * 4;
        const int n = base >> 5, m = base & 31;
        bf16x4 v;
        v[0] = (bf16)satt[n][m];     v[1] = (bf16)satt[n][m + 1];
        v[2] = (bf16)satt[n][m + 2]; v[3] = (bf16)satt[n][m + 3];
        *(bf16x4*)&attb[(long)g * 1024 + base] = v;
    }
}

// ---------------- ctx = att @ X via MFMA, grid (512 groups, 8 d-chunks) ----------------
// Per block: [32x32]bf16 @ [32x256]bf16 -> ctx[32x256]. X tile staged in LDS with
// stride 258 (transposed B-frag reads conflict-free: quads offset 8 banks).
__global__ __launch_bounds__(256) void ctx_kernel(const bf16* __restrict__ attb,
                                                  const bf16* __restrict__ Xb,
                                                  bf16* __restrict__ ctx) {
    __shared__ bf16 sX[32 * 258];
    const int g   = blockIdx.x;
    const int dch = blockIdx.y;
    const int tid = threadIdx.x;
    const long R0 = (long)g * 32;
    const int d0  = dch * 256;

    // stage X tile [32 rows x 256 cols]
    {
        const int r  = tid >> 3;
        const int c0 = (tid & 7) * 32;
        const bf16* src = Xb + (R0 + r) * C_D + d0 + c0;
#pragma unroll
        for (int i = 0; i < 4; i++) {
            bf16x8 v = *(const bf16x8*)(src + i * 8);
            *(bf16x8*)&sX[r * 258 + c0 + i * 8] = v;
        }
    }
    __syncthreads();

    const int lane = tid & 63;
    const int wave = tid >> 6;
    const int rr   = lane & 15;
    const int q    = lane >> 4;

    // A-frags straight from global (att is L2-hot, 16B/lane)
    bf16x8 af[2];
#pragma unroll
    for (int i = 0; i < 2; i++)
        af[i] = *(const bf16x8*)&attb[(long)g * 1024 + (i * 16 + rr) * 32 + q * 8];

    floatx4 acc[2][4];
#pragma unroll
    for (int i = 0; i < 2; i++)
#pragma unroll
        for (int j = 0; j < 4; j++) acc[i][j] = (floatx4){0.f, 0.f, 0.f, 0.f};

#pragma unroll
    for (int j = 0; j < 4; j++) {
        const int dl = wave * 64 + j * 16 + rr;
        bf16x8 bf_;
#pragma unroll
        for (int jj = 0; jj < 8; jj++)
            bf_[jj] = sX[(q * 8 + jj) * 258 + dl];
#pragma unroll
        for (int i = 0; i < 2; i++)
            acc[i][j] = __builtin_amdgcn_mfma_f32_16x16x32_bf16(af[i], bf_, acc[i][j], 0, 0, 0);
    }

    const int rbase = q * 4;
#pragma unroll
    for (int i = 0; i < 2; i++)
#pragma unroll
        for (int j = 0; j < 4; j++)
#pragma unroll
            for (int r = 0; r < 4; r++)
                ctx[(R0 + i * 16 + rbase + r) * C_D + d0 + wave * 64 + j * 16 + rr]
                    = (bf16)acc[i][j][r];
}

// ---------------- att2: logits + softmax per class (64 blocks x 256) ----------------
__global__ __launch_bounds__(256) void att2_kernel(const float* __restrict__ p_e,
                                                   const float* __restrict__ fa_e,
                                                   float* __restrict__ att2f) {
    __shared__ float spe[5][256];
    __shared__ float red[256];
    __shared__ float att[5][256];
    const int c   = blockIdx.x;
    const int tid = threadIdx.x;

    for (int t = tid; t < 5 * 256; t += 256)
        spe[t >> 8][t & 255] = p_e[(long)c * 5 * 256 + t] * (1.0f / 16.0f);
    __syncthreads();

    // logits: thread = n, float4 over o
    {
        const float4* fa = (const float4*)(fa_e + ((long)c * 256 + tid) * 256);
        float acc[5] = {0.f, 0.f, 0.f, 0.f, 0.f};
        for (int o4 = 0; o4 < 64; o4++) {
            float4 f = fa[o4];
#pragma unroll
            for (int p = 0; p < 5; p++) {
                float4 s = *(const float4*)&spe[p][o4 * 4];
                acc[p] += s.x * f.x + s.y * f.y + s.z * f.z + s.w * f.w;
            }
        }
#pragma unroll
        for (int p = 0; p < 5; p++) att[p][tid] = acc[p];
    }
    __syncthreads();

    for (int p = 0; p < 5; p++) {
        float v = att[p][tid];
        red[tid] = v; __syncthreads();
        for (int s = 128; s > 0; s >>= 1) { if (tid < s) red[tid] = fmaxf(red[tid], red[tid + s]); __syncthreads(); }
        float mx = red[0]; __syncthreads();
        float ev = __expf(v - mx);
        red[tid] = ev; __syncthreads();
        for (int s = 128; s > 0; s >>= 1) { if (tid < s) red[tid] += red[tid + s]; __syncthreads(); }
        float sum = red[0]; __syncthreads();
        att2f[((long)c * 5 + p) * 256 + tid] = ev / sum;
    }
}

// ---------------- out = att2 @ Y, grid (64 classes, 8 d-chunks) x 256 ----------------
__global__ __launch_bounds__(256) void out_kernel(const float* __restrict__ att2f,
                                                  const bf16* __restrict__ Yb,
                                                  float* __restrict__ out) {
    __shared__ float s2[5][256];
    const int c   = blockIdx.x;
    const int ch  = blockIdx.y;
    const int tid = threadIdx.x;

    for (int t = tid; t < 5 * 256; t += 256)
        s2[t >> 8][t & 255] = att2f[(long)c * 5 * 256 + t];
    __syncthreads();

    const int d = ch * 256 + tid;
    const bf16* Yc = Yb + (long)c * C_O * C_D + d;
    float acc[5] = {0.f, 0.f, 0.f, 0.f, 0.f};
    for (int n4 = 0; n4 < 64; n4++) {
        float y0 = (float)Yc[(long)(n4 * 4 + 0) * C_D];
        float y1 = (float)Yc[(long)(n4 * 4 + 1) * C_D];
        float y2 = (float)Yc[(long)(n4 * 4 + 2) * C_D];
        float y3 = (float)Yc[(long)(n4 * 4 + 3) * C_D];
#pragma unroll
        for (int p = 0; p < 5; p++) {
            float4 a = *(const float4*)&s2[p][n4 * 4];
            acc[p] += a.x * y0 + a.y * y1 + a.z * y2 + a.w * y3;
        }
    }
#pragma unroll
    for (int p = 0; p < 5; p++)
        out[((long)c * 5 + p) * C_D + d] = acc[p];
}

extern "C" void kernel_launch(void* const* d_in, const int* in_sizes, int n_in,
                              void* d_out, int out_size, void* d_ws, size_t ws_size,
                              hipStream_t stream) {
    const float* X   = (const float*)d_in[0];
    const float* P   = (const float*)d_in[1];
    const float* W1  = (const float*)d_in[2];
    const float* T   = (const float*)d_in[3];
    const float* Wi1 = (const float*)d_in[4];
    const float* Wi2 = (const float*)d_in[5];
    float* out = (float*)d_out;

    char* ws = (char*)d_ws;
    size_t off = 0;
    auto alloc = [&](size_t bytes) -> void* {
        void* p = ws + off;
        off += (bytes + 255) & ~(size_t)255;
        return p;
    };
    const size_t NX = (size_t)C_M * C_D;
    bf16*  Xb   = (bf16*)alloc(NX * 2);
    bf16*  ctxb = (bf16*)alloc(NX * 2);
    bf16*  Tb   = (bf16*)alloc((size_t)C_D * C_D * 2);
    bf16*  W1b  = (bf16*)alloc((size_t)C_O * C_D * 2);
    bf16*  Wi1b = (bf16*)alloc((size_t)C_O * C_D * 2);
    bf16*  W2b  = (bf16*)alloc((size_t)C_O * C_D * 2);
    bf16*  Yb   = (bf16*)alloc(NX * 2);
    float* eBuf = (float*)alloc((size_t)C_M * C_O * 4);
    bf16*  attb = (bf16*)alloc((size_t)512 * 1024 * 2);   // aliased: att2f after ctx
    float* peBuf= (float*)alloc((size_t)C_CLASS * C_P * C_O * 4);
    float* faBuf = eBuf;            // e dead after att_kernel
    float* att2f = (float*)attb;    // attb dead after ctx_kernel (0.33MB < 1MB)

    // 1. weights -> bf16
    const int nConv4 = (C_D * C_D + 3 * C_O * C_D) / 4;
    convw_kernel<<<nConv4 / 256, 256, 0, stream>>>(T, W1, Wi1, Wi2, Tb, W1b, Wi1b, W2b);

    // 2. e = X . W1^T [16384,256]; n0==0 blocks emit Xb
    gemm64<1><<<dim3(C_M / 64, 2), 256, 0, stream>>>(X, W1b, eBuf, Xb);

    // 3. S + softmax -> att (bf16)
    att_kernel<<<C_CLASS * C_GROUPS, 256, 0, stream>>>(eBuf, attb);

    // 4. ctx = att @ X (batched MFMA)
    ctx_kernel<<<dim3(C_CLASS * C_GROUPS, 8), 256, 0, stream>>>(attb, Xb, ctxb);

    // 5. Y = bf16(Xb + relu(ctx . T^T)) — 256x256 tile, compiler-counted lgkmcnt pipeline
    gemm_relu<<<dim3((C_M / 256) * (C_D / 256)), 512, 0, stream>>>(ctxb, Tb, Xb, Yb);

    // 6. fa_e = Y . Wi1^T [16384,256]
    gemm64<0><<<dim3(C_M / 64, 2), 256, 0, stream>>>(Yb, Wi1b, faBuf, nullptr);

    // 7. p_e = P . W2^T [320,256] (M=320 = 5 blocks)
    gemm64<1><<<dim3(C_CLASS * C_P / 64, 2), 256, 0, stream>>>(P, W2b, peBuf, nullptr);

    // 8. att2 = softmax(p_e . fa_e^T / 16)
    att2_kernel<<<C_CLASS, 256, 0, stream>>>(peBuf, faBuf, att2f);

    // 9. out = att2 @ Y
    out_kernel<<<dim3(C_CLASS, 8), 256, 0, stream>>>(att2f, Yb, out);
}